// Round 6
// baseline (513.339 us; speedup 1.0000x reference)
//
#include <hip/hip_runtime.h>
#include <hip/hip_fp16.h>
#include <math.h>

#define NN 100000
#define NE 3200000
#define FIN 256
#define HID 16
#define NC 32
#define NBUK 782          // ceil(NN/128); bucket = dst >> 7
#define SC_BLOCKS 250
#define SC_TILE 12800     // NE = 250 * 12800; 50 edges/thread
#define SC_EPT 50
#define SK 26             // sort staging regs: 26*256=6656 >> mean 4092

// ---------------------------------------------------------------------------
// K1: tiled node GEMM for layer 1.  C[100000 x 48] = x[100000 x 256] @ Wc.
// Block tile: 128 nodes x 48 outs, K-chunks of 64. Coalesced float4 staging
// of x into LDS (row pad 65 => conflict-free column reads). Thread = 2 nodes
// (nl, nl+64) x 12 outs (oc).
//   xs1p[n*16+c] = half2( C[c], C[16+c] )            (kernel-transformed)
//   r1h[n*8+w]   = half2( C[32+2w]+b, C[33+2w]+b )   (root part)
// ---------------------------------------------------------------------------
__global__ __launch_bounds__(256) void k_gemm1(
    const float* __restrict__ x, const float* __restrict__ W1,
    const float* __restrict__ root1, const float* __restrict__ bias1,
    __half2* __restrict__ xs1p, __half2* __restrict__ r1h)
{
    __shared__ float xt[128 * 65];   // 33.3 KB
    __shared__ float wt[64 * 48];    // 12 KB
    int t = threadIdx.x;
    int n0 = blockIdx.x * 128;
    int nl = t & 63, oc = t >> 6;

    float accA[12], accB[12];
    #pragma unroll
    for (int j = 0; j < 12; ++j) { accA[j] = 0.f; accB[j] = 0.f; }

    for (int c = 0; c < 4; ++c) {
        __syncthreads();
        // stage x tile: 128 rows x 16 float4, coalesced (lane->consecutive f4)
        #pragma unroll
        for (int it = 0; it < 8; ++it) {
            int idx = it * 256 + t;
            int r = idx >> 4, kq = idx & 15;
            int n = n0 + r;
            const float4* srcp =
                (const float4*)(x + (size_t)(n < NN ? n : 0) * FIN + c * 64);
            float4 v = srcp[kq];
            float* dp = &xt[r * 65 + kq * 4];
            dp[0] = v.x; dp[1] = v.y; dp[2] = v.z; dp[3] = v.w;
        }
        // stage weight chunk: 64 k-rows x 48 outs
        for (int i = t; i < 64 * 48; i += 256) {
            int kk = i / 48, j = i - kk * 48;
            int k = c * 64 + kk;
            float v;
            if (j < 16)      v = W1[k * 16 + j];
            else if (j < 32) v = W1[FIN * 16 + k * 16 + (j - 16)];
            else             v = root1[k * 16 + (j - 32)];
            wt[i] = v;
        }
        __syncthreads();
        #pragma unroll 4
        for (int kk = 0; kk < 64; ++kk) {
            float xa = xt[nl * 65 + kk];
            float xb = xt[(nl + 64) * 65 + kk];
            const float4* wv = (const float4*)&wt[kk * 48 + 12 * oc];
            float4 w0 = wv[0], w1 = wv[1], w2 = wv[2];
            accA[0] += xa * w0.x; accA[1] += xa * w0.y;
            accA[2] += xa * w0.z; accA[3] += xa * w0.w;
            accA[4] += xa * w1.x; accA[5] += xa * w1.y;
            accA[6] += xa * w1.z; accA[7] += xa * w1.w;
            accA[8] += xa * w2.x; accA[9] += xa * w2.y;
            accA[10] += xa * w2.z; accA[11] += xa * w2.w;
            accB[0] += xb * w0.x; accB[1] += xb * w0.y;
            accB[2] += xb * w0.z; accB[3] += xb * w0.w;
            accB[4] += xb * w1.x; accB[5] += xb * w1.y;
            accB[6] += xb * w1.z; accB[7] += xb * w1.w;
            accB[8] += xb * w2.x; accB[9] += xb * w2.y;
            accB[10] += xb * w2.z; accB[11] += xb * w2.w;
        }
    }

    // epilogue: transpose through LDS (reuse xt), emit packed fp16 tables
    __syncthreads();
    #pragma unroll
    for (int j = 0; j < 12; ++j) {
        xt[nl * 49 + oc * 12 + j] = accA[j];
        xt[(nl + 64) * 49 + oc * 12 + j] = accB[j];
    }
    __syncthreads();
    int n_loc = t >> 1, hf = t & 1;
    int n = n0 + n_loc;
    if (n < NN) {
        const float* o = &xt[n_loc * 49];
        __half2* xs = xs1p + (size_t)n * 16 + hf * 8;
        #pragma unroll
        for (int cc = 0; cc < 8; ++cc) {
            int ch = hf * 8 + cc;
            xs[cc] = __floats2half2_rn(o[ch], o[16 + ch]);
        }
        __half2* rr = r1h + (size_t)n * 8 + hf * 4;
        #pragma unroll
        for (int wv2 = 0; wv2 < 4; ++wv2) {
            int ch = hf * 8 + 2 * wv2;
            rr[wv2] = __floats2half2_rn(o[32 + ch] + bias1[ch],
                                        o[33 + ch] + bias1[ch + 1]);
        }
    }
}

// ---------------------------------------------------------------------------
// Bucket histogram (LDS-merged counts of dst>>7).
// ---------------------------------------------------------------------------
__global__ __launch_bounds__(256) void k_bhist(const int* __restrict__ ei,
                                               int* __restrict__ bhist)
{
    __shared__ int h[NBUK];
    int t = threadIdx.x;
    for (int b = t; b < NBUK; b += 256) h[b] = 0;
    __syncthreads();
    const int* dstp = ei + NE + blockIdx.x * SC_TILE;
    for (int k = 0; k < SC_EPT; ++k)
        atomicAdd(&h[dstp[t + k * 256] >> 7], 1);
    __syncthreads();
    for (int b = t; b < NBUK; b += 256) {
        int c = h[b];
        if (c) atomicAdd(&bhist[b], c);
    }
}

// ---------------------------------------------------------------------------
// Exclusive scan of 782 bucket counts; writes bstart (pristine), gcur
// (mutable cursors), and the rowptr sentinel.
// ---------------------------------------------------------------------------
__global__ __launch_bounds__(1024) void k_bscan(const int* __restrict__ bhist,
                                                int* __restrict__ bstart,
                                                int* __restrict__ gcur,
                                                int* __restrict__ rowptr)
{
    __shared__ int s[1024];
    int t = threadIdx.x;
    int v = (t < NBUK) ? bhist[t] : 0;
    s[t] = v;
    __syncthreads();
    for (int off = 1; off < 1024; off <<= 1) {
        int a = (t >= off) ? s[t - off] : 0;
        __syncthreads();
        s[t] += a;
        __syncthreads();
    }
    if (t < NBUK) {
        int excl = s[t] - v;
        bstart[t] = excl;
        gcur[t] = excl;
    }
    if (t == 0) rowptr[NN] = NE;
}

// ---------------------------------------------------------------------------
// Binscatter: per-block per-bucket run reservation -> contiguous run writes.
// Record: .x = src | (dst&127)<<17 ; .y = f32 bits of clipped u.
// ---------------------------------------------------------------------------
__global__ __launch_bounds__(256) void k_binscatter(
    const int* __restrict__ ei, const float* __restrict__ ea,
    int* __restrict__ gcur, uint2* __restrict__ rec)
{
    __shared__ int h[NBUK];
    int t = threadIdx.x;
    for (int b = t; b < NBUK; b += 256) h[b] = 0;
    __syncthreads();
    int e0 = blockIdx.x * SC_TILE;
    for (int k = 0; k < SC_EPT; ++k)
        atomicAdd(&h[ei[NE + e0 + t + k * 256] >> 7], 1);
    __syncthreads();
    for (int b = t; b < NBUK; b += 256)
        h[b] = atomicAdd(&gcur[b], h[b]);   // LDS now holds global cursors
    __syncthreads();
    for (int k = 0; k < SC_EPT; ++k) {
        int e = e0 + t + k * 256;
        int src = ei[e];
        int dst = ei[NE + e];
        float u = fminf(fmaxf(ea[e], 0.f), 1.f);
        int pos = atomicAdd(&h[dst >> 7], 1);
        uint2 r;
        r.x = (unsigned)src | ((unsigned)(dst & 127) << 17);
        r.y = __float_as_uint(u);
        rec[pos] = r;
    }
}

// ---------------------------------------------------------------------------
// In-bucket counting sort (in place) -> full per-node CSR. One block/bucket.
// ---------------------------------------------------------------------------
__global__ __launch_bounds__(256) void k_sort(
    const int* __restrict__ bstart, const int* __restrict__ bhist,
    uint2* __restrict__ rec, int* __restrict__ rowptr)
{
    __shared__ int cnt[128], cur[128], ss[128];
    int t = threadIdx.x;
    if (t < 128) cnt[t] = 0;
    __syncthreads();
    int start = bstart[blockIdx.x], m = bhist[blockIdx.x];
    uint2 r[SK];
    int nr = 0;
    for (int i = start + t; i < start + m; i += 256) {
        uint2 v = rec[i];
        if (nr < SK) r[nr++] = v;
        atomicAdd(&cnt[(v.x >> 17) & 127], 1);
    }
    __syncthreads();
    if (t < 128) ss[t] = cnt[t];
    __syncthreads();
    for (int off = 1; off < 128; off <<= 1) {
        int a = (t < 128 && t >= off) ? ss[t - off] : 0;
        __syncthreads();
        if (t < 128) ss[t] += a;
        __syncthreads();
    }
    if (t < 128) {
        int excl = ss[t] - cnt[t];
        cur[t] = excl;
        int n = blockIdx.x * 128 + t;
        if (n < NN) rowptr[n] = start + excl;
    }
    __syncthreads();
    for (int k = 0; k < nr; ++k) {
        int dl = (int)(r[k].x >> 17) & 127;
        int p = atomicAdd(&cur[dl], 1);
        rec[start + p] = r[k];
    }
}

// ---------------------------------------------------------------------------
// Agg layer 1 (register accumulation, 8 lanes/node, 4-deep gather batching)
// + fused ELU + layer-2 node GEMM epilogue.
// ---------------------------------------------------------------------------
__global__ __launch_bounds__(256) void k_agg1g2(
    const int* __restrict__ rowptr, const uint2* __restrict__ rec,
    const uint2* __restrict__ xs, const __half2* __restrict__ r1h,
    const float* __restrict__ W2, const float* __restrict__ root2,
    const float* __restrict__ bias2,
    __half2* __restrict__ hs2p, float* __restrict__ r2)
{
    __shared__ float hsm[32 * 17];
    __shared__ float wgt[1568];   // W2[1024] | root2[512] | bias2[32]
    int t = threadIdx.x;
    for (int i = t; i < 1568; i += 256)
        wgt[i] = (i < 1024) ? W2[i] : (i < 1536 ? root2[i - 1024] : bias2[i - 1536]);

    int nl = t >> 3, j = t & 7;
    int n = blockIdx.x * 32 + nl;          // grid 3125: n < NN always
    int s = rowptr[n], e = rowptr[n + 1];
    int d = e - s;
    float a0 = 0.f, a1 = 0.f;

    #define ACC1(q, g) {                                            \
        float u = __uint_as_float((q).y);                           \
        float2 f0 = __half22float2(*(const __half2*)&(g).x);        \
        float2 f1 = __half22float2(*(const __half2*)&(g).y);        \
        a0 += (1.f - u) * f0.x + u * f0.y;                          \
        a1 += (1.f - u) * f1.x + u * f1.y; }

    int k = s;
    for (; k + 4 <= e; k += 4) {
        uint2 q0 = rec[k], q1 = rec[k+1], q2 = rec[k+2], q3 = rec[k+3];
        uint2 g0 = xs[(size_t)(q0.x & 0x1FFFF) * 8 + j];
        uint2 g1 = xs[(size_t)(q1.x & 0x1FFFF) * 8 + j];
        uint2 g2 = xs[(size_t)(q2.x & 0x1FFFF) * 8 + j];
        uint2 g3 = xs[(size_t)(q3.x & 0x1FFFF) * 8 + j];
        ACC1(q0, g0) ACC1(q1, g1) ACC1(q2, g2) ACC1(q3, g3)
    }
    for (; k < e; ++k) {
        uint2 q = rec[k];
        uint2 g = xs[(size_t)(q.x & 0x1FFFF) * 8 + j];
        ACC1(q, g)
    }
    #undef ACC1

    float inv = 1.f / fmaxf((float)d, 1.f);
    float2 rr = __half22float2(r1h[(size_t)n * 8 + j]);
    float v0 = a0 * inv + rr.x;
    float v1 = a1 * inv + rr.y;
    v0 = v0 > 0.f ? v0 : expm1f(v0);
    v1 = v1 > 0.f ? v1 : expm1f(v1);
    hsm[nl * 17 + 2 * j] = v0;
    hsm[nl * 17 + 2 * j + 1] = v1;
    __syncthreads();

    float h[16];
    #pragma unroll
    for (int kk = 0; kk < 16; ++kk) h[kk] = hsm[nl * 17 + kk];
    __half2* hp = hs2p + (size_t)n * 32;
    float* r2p = r2 + (size_t)n * 32;
    #pragma unroll
    for (int mo = 0; mo < 4; ++mo) {
        int c = j + 8 * mo;
        float d0 = 0.f, d1 = 0.f, dr = wgt[1536 + c];
        #pragma unroll
        for (int kk = 0; kk < 16; ++kk) {
            d0 += h[kk] * wgt[kk * 32 + c];
            d1 += h[kk] * wgt[512 + kk * 32 + c];
            dr += h[kk] * wgt[1024 + kk * 32 + c];
        }
        hp[c] = __floats2half2_rn(d0, d1);
        r2p[c] = dr;
    }
}

// ---------------------------------------------------------------------------
// Agg layer 2 (register accumulation, 16 lanes/node) + fused mean + root +
// log-softmax epilogue -> d_out.
// ---------------------------------------------------------------------------
__global__ __launch_bounds__(256) void k_agg2(
    const int* __restrict__ rowptr, const uint2* __restrict__ rec,
    const uint2* __restrict__ hs, const float* __restrict__ r2,
    float* __restrict__ out)
{
    int t = threadIdx.x;
    int nl = t >> 4, j = t & 15;
    int n = blockIdx.x * 16 + nl;          // grid 6250: n < NN always
    int s = rowptr[n], e = rowptr[n + 1];
    int d = e - s;
    float a0 = 0.f, a1 = 0.f;

    #define ACC2(q, g) {                                            \
        float u = __uint_as_float((q).y);                           \
        float2 f0 = __half22float2(*(const __half2*)&(g).x);        \
        float2 f1 = __half22float2(*(const __half2*)&(g).y);        \
        a0 += (1.f - u) * f0.x + u * f0.y;                          \
        a1 += (1.f - u) * f1.x + u * f1.y; }

    int k = s;
    for (; k + 4 <= e; k += 4) {
        uint2 q0 = rec[k], q1 = rec[k+1], q2 = rec[k+2], q3 = rec[k+3];
        uint2 g0 = hs[(size_t)(q0.x & 0x1FFFF) * 16 + j];
        uint2 g1 = hs[(size_t)(q1.x & 0x1FFFF) * 16 + j];
        uint2 g2 = hs[(size_t)(q2.x & 0x1FFFF) * 16 + j];
        uint2 g3 = hs[(size_t)(q3.x & 0x1FFFF) * 16 + j];
        ACC2(q0, g0) ACC2(q1, g1) ACC2(q2, g2) ACC2(q3, g3)
    }
    for (; k < e; ++k) {
        uint2 q = rec[k];
        uint2 g = hs[(size_t)(q.x & 0x1FFFF) * 16 + j];
        ACC2(q, g)
    }
    #undef ACC2

    float inv = 1.f / fmaxf((float)d, 1.f);
    float2 rr = ((const float2*)r2)[(size_t)n * 16 + j];
    float v0 = a0 * inv + rr.x;
    float v1 = a1 * inv + rr.y;

    float m = fmaxf(v0, v1);
    #pragma unroll
    for (int off = 1; off < 16; off <<= 1)
        m = fmaxf(m, __shfl_xor(m, off, 16));
    float sm = expf(v0 - m) + expf(v1 - m);
    #pragma unroll
    for (int off = 1; off < 16; off <<= 1)
        sm += __shfl_xor(sm, off, 16);
    float ls = logf(sm);
    ((float2*)out)[(size_t)n * 16 + j] = make_float2(v0 - m - ls, v1 - m - ls);
}

// ---------------------------------------------------------------------------
extern "C" void kernel_launch(void* const* d_in, const int* in_sizes, int n_in,
                              void* d_out, int out_size, void* d_ws, size_t ws_size,
                              hipStream_t stream)
{
    const float* x     = (const float*)d_in[0];
    const float* ea    = (const float*)d_in[1];
    const float* W1    = (const float*)d_in[2];
    const float* root1 = (const float*)d_in[3];
    const float* bias1 = (const float*)d_in[4];
    const float* W2    = (const float*)d_in[5];
    const float* root2 = (const float*)d_in[6];
    const float* bias2 = (const float*)d_in[7];
    const int*   ei    = (const int*)d_in[8];
    float* out = (float*)d_out;

    // Workspace layout (float units; half2 = 4 B):
    float* ws = (float*)d_ws;
    __half2* xs1p = (__half2*)ws;                      // NN*16 fl
    __half2* r1h  = (__half2*)(ws + (size_t)NN * 16);  // NN*8  fl
    __half2* hs2p = (__half2*)(ws + (size_t)NN * 24);  // NN*32 fl
    float*   r2   = ws + (size_t)NN * 56;              // NN*32 fl
    uint2*   rec  = (uint2*)(ws + (size_t)NN * 88);    // NE uint2 = NN*64 fl
    int*     iws  = (int*)(ws + (size_t)NN * 152);
    int* rowptr = iws;                   // NN+1
    int* bhist  = iws + NN + 1;          // NBUK
    int* bstart = bhist + NBUK;          // NBUK
    int* gcur   = bstart + NBUK;         // NBUK
    // total ≈ NN*153 floats + 9.4 KB ≈ 61.2 MB

    hipMemsetAsync(bhist, 0, NBUK * sizeof(int), stream);

    k_gemm1<<<NBUK, 256, 0, stream>>>(x, W1, root1, bias1, xs1p, r1h);
    k_bhist<<<SC_BLOCKS, 256, 0, stream>>>(ei, bhist);
    k_bscan<<<1, 1024, 0, stream>>>(bhist, bstart, gcur, rowptr);
    k_binscatter<<<SC_BLOCKS, 256, 0, stream>>>(ei, ea, gcur, rec);
    k_sort<<<NBUK, 256, 0, stream>>>(bstart, bhist, rec, rowptr);
    k_agg1g2<<<(NN * 8) / 256, 256, 0, stream>>>(rowptr, rec, (const uint2*)xs1p,
                                                 r1h, W2, root2, bias2, hs2p, r2);
    k_agg2<<<(NN * 16) / 256, 256, 0, stream>>>(rowptr, rec, (const uint2*)hs2p,
                                                r2, out);
}